// Round 16
// baseline (329.573 us; speedup 1.0000x reference)
//
#include <hip/hip_runtime.h>
#include <hip/hip_bf16.h>

using bf16 = __hip_bfloat16;
typedef __attribute__((ext_vector_type(8))) short short8;
typedef __attribute__((ext_vector_type(4))) float f32x4;
typedef __attribute__((ext_vector_type(4))) unsigned int u32x4;

__device__ __forceinline__ float b2f(bf16 v){ return __bfloat162float(v); }
__device__ __forceinline__ float sigf(float v){ return 1.f/(1.f + __expf(-v)); }
__device__ __forceinline__ float ldv(const float* p, int i){ return p[i]; }
__device__ __forceinline__ float ldv(const bf16* p, int i){ return b2f(p[i]); }
__device__ __forceinline__ void stv(float* p, int i, float v){ p[i] = v; }
__device__ __forceinline__ void stv(bf16* p, int i, float v){ p[i] = __float2bfloat16(v); }
__device__ __forceinline__ float bfe(short8 v, int j){
  unsigned short s = (unsigned short)v[j];
  return b2f(*(bf16*)&s);
}

__device__ __forceinline__ void ld2v(const float* p, float& a, float& b){
  float2 v = *(const float2*)p; a = v.x; b = v.y;
}
__device__ __forceinline__ void ld2v(const bf16* p, float& a, float& b){
  unsigned int u = *(const unsigned int*)p;
  unsigned short s0 = (unsigned short)(u & 0xFFFF), s1 = (unsigned short)(u >> 16);
  a = b2f(*(bf16*)&s0); b = b2f(*(bf16*)&s1);
}
__device__ __forceinline__ void ld8(const bf16* s, unsigned int* pk){
  short8 v = *(const short8*)s;
  #pragma unroll
  for (int e = 0; e < 4; e++)
    pk[e] = (unsigned int)(unsigned short)v[2*e]
          | ((unsigned int)(unsigned short)v[2*e+1] << 16);
}
__device__ __forceinline__ void ld8(const float* s, unsigned int* pk){
  f32x4 a = *(const f32x4*)s, c = *(const f32x4*)(s + 4);
  float vals[8] = {a[0],a[1],a[2],a[3],c[0],c[1],c[2],c[3]};
  #pragma unroll
  for (int e = 0; e < 4; e++){
    bf16 h0 = __float2bfloat16(vals[2*e]), h1 = __float2bfloat16(vals[2*e+1]);
    pk[e] = (unsigned int)*(unsigned short*)&h0
          | ((unsigned int)*(unsigned short*)&h1 << 16);
  }
}

// ---------------------------------------------------------------------------
// K0: dtype detect. flag=1 => inputs are f32.
// ---------------------------------------------------------------------------
__global__ __launch_bounds__(256) void k_detect(const unsigned short* xs, int* flag){
  __shared__ int cnt;
  if (threadIdx.x == 0) cnt = 0;
  __syncthreads();
  int local = 0;
  for (int i = threadIdx.x; i < 16384; i += 256){
    if (((xs[i] >> 7) & 0xFF) == 0xFF) local++;
  }
  if (local) atomicAdd(&cnt, local);
  __syncthreads();
  if (threadIdx.x == 0) *flag = (cnt > 0) ? 1 : 0;
}

// ---------------------------------------------------------------------------
// K0b: canonicalize params. 18 = w_def REMAPPED tap-major [co][tap*64+c];
// 19/20 = w_off/w_g1 remapped [co][chunk][tap][c32]; 23 = w_g2 transposed.
// ---------------------------------------------------------------------------
struct ParamSrc { const void* p[18]; };

__global__ __launch_bounds__(256) void k_convert(ParamSrc ps, const int* flagp,
    float* cpar, bf16* wdefb, bf16* woffb, bf16* wg1b, bf16* wcrossb, bf16* woutb,
    float* cwT){
  static constexpr int n[24]   = {41472,18,147456,131072,147456,64,64,64,64,64,
                                  16384,256,65536,256,256,256,256,256,
                                  147456,73728,147456,131072,65536,16384};
  static constexpr int off[18] = {0,41472,41504,188960,320032,467488,467552,467616,
                                  467680,467744,467808,484192,484448,549984,550240,
                                  550496,550752,551008};
  const int s = blockIdx.y;
  const bool f32 = (*flagp != 0);
  if (s == 23){
    for (int i = blockIdx.x * 256 + threadIdx.x; i < 16384; i += gridDim.x * 256){
      const int c = i >> 8, co = i & 255;
      if (f32) cwT[i] = ((const float*)ps.p[10])[co * 64 + c];
      else     cwT[i] = b2f(((const bf16*)ps.p[10])[co * 64 + c]);
    }
    return;
  }
  if (s >= 18){
    static constexpr int srcs[5] = {2, 0, 4, 3, 12};
    const int src_slot = srcs[s - 18];
    bf16* dst = (s == 18) ? wdefb : (s == 19) ? woffb : (s == 20) ? wg1b
              : (s == 21) ? wcrossb : woutb;
    const int nsrc = (s == 19) ? 41472 : n[s];
    for (int i = blockIdx.x * 256 + threadIdx.x; i < n[s]; i += gridDim.x * 256){
      int srcIdx = i;
      if (s == 19 || s == 20){
        const int co = i / 2304, rem = i % 2304;
        const int chunk = rem / 288, r2 = rem % 288;
        const int tap = r2 >> 5, cl = r2 & 31;
        srcIdx = co * 2304 + (chunk * 32 + cl) * 9 + tap;
      } else if (s == 18){
        const int co = i / 576, rem = i % 576;
        const int tap = rem >> 6, c = rem & 63;
        srcIdx = co * 576 + c * 9 + tap;
      }
      if (f32){
        const float* src = (const float*)ps.p[src_slot];
        dst[i] = (srcIdx < nsrc) ? __float2bfloat16(src[srcIdx]) : __float2bfloat16(0.f);
      } else {
        const bf16* src = (const bf16*)ps.p[src_slot];
        dst[i] = (srcIdx < nsrc) ? src[srcIdx] : __float2bfloat16(0.f);
      }
    }
    return;
  }
  float* dst = cpar + off[s];
  if (f32){
    const float* src = (const float*)ps.p[s];
    for (int i = blockIdx.x * 256 + threadIdx.x; i < n[s]; i += gridDim.x * 256)
      dst[i] = src[i];
  } else {
    const bf16* src = (const bf16*)ps.p[s];
    for (int i = blockIdx.x * 256 + threadIdx.x; i < n[s]; i += gridDim.x * 256)
      dst[i] = b2f(src[i]);
  }
}

// ---------------------------------------------------------------------------
// K1b: NHWC bf16 staging for deform gather: x_t[b][g][p=4096][cg=64].
// ---------------------------------------------------------------------------
template<typename T>
__device__ __forceinline__ void xt_body(const T* __restrict__ x, bf16* __restrict__ xt){
  __shared__ float lds[64][65];
  const int bx = blockIdx.x;
  const int b = bx >> 8, y = (bx >> 2) & 63, g = bx & 3;
  const int t = threadIdx.x;
  const int px = t & 63, cq = t >> 6;
  #pragma unroll
  for (int it = 0; it < 16; it++){
    const int ch = cq * 16 + it;
    lds[ch][px] = ldv(x, ((b * 256 + g * 64 + ch) * 64 + y) * 64 + px);
  }
  __syncthreads();
  const int ch = t & 63, pb = t >> 6;
  bf16* ob = xt + ((b * 4 + g) * 4096 + y * 64) * 64 + ch;
  #pragma unroll
  for (int i = 0; i < 16; i++){
    const int p = pb * 16 + i;
    ob[p * 64] = __float2bfloat16(lds[ch][p]);
  }
}

__global__ __launch_bounds__(256) void k_xt(const void* x, const int* flagp, bf16* xt){
  if (*flagp) xt_body((const float*)x, xt);
  else        xt_body((const bf16*)x, xt);
}

// ---------------------------------------------------------------------------
// conv3 RAW split-K, TILE-STAGED (R12/R15 structure — measured good).
// ---------------------------------------------------------------------------
template<typename T, int COT>
__device__ __forceinline__ void conv3_raw(const T* __restrict__ xin,
    const bf16* __restrict__ wb, float* __restrict__ outp, int co_lim,
    unsigned short* xt16, int cc_begin){
  const int bx = blockIdx.x;
  const int b = bx >> 6, y = bx & 63;
  const int t = threadIdx.x;
  const int l = t & 63, w = t >> 6;
  const int lm = l & 15, lq = l >> 4;
  const int px = w * 16 + lm;
  f32x4 acc[COT];
  #pragma unroll
  for (int m = 0; m < COT; m++) acc[m] = (f32x4){0.f,0.f,0.f,0.f};

  #pragma unroll
  for (int ch_i = 0; ch_i < 2; ch_i++){
    const int cc = cc_begin + ch_i * 32;
    __syncthreads();
    if (t < 96){
      const int c = t / 3, r = t - c * 3;
      xt16[c * 210 + r * 70 + 3]  = 0;
      xt16[c * 210 + r * 70 + 68] = 0;
    }
    #pragma unroll
    for (int it = 0; it < 3; it++){
      const int u = t + it * 256;
      const int pb = u & 7;
      const int cr = u >> 3;
      const int c = cr / 3, r = cr - c * 3;
      const int yy = y + r - 1;
      const int px0 = pb * 8;
      unsigned int pk[4];
      if ((unsigned)yy < 64u){
        ld8(xin + (b * 256 + cc + c) * 4096 + yy * 64 + px0, pk);
      } else {
        pk[0] = pk[1] = pk[2] = pk[3] = 0;
      }
      unsigned int* dp = (unsigned int*)(xt16 + c * 210 + r * 70 + 4 + px0);
      dp[0] = pk[0]; dp[1] = pk[1]; dp[2] = pk[2]; dp[3] = pk[3];
    }
    __syncthreads();
    const int chunkG = cc >> 5;
    const unsigned short* bt = xt16 + 3 + px;
    #pragma unroll
    for (int tap = 0; tap < 9; tap++){
      const int ti = tap / 3, tj = tap - ti * 3;
      short8 bfr;
      #pragma unroll
      for (int j = 0; j < 8; j++)
        bfr[j] = (short)bt[(lq * 8 + j) * 210 + ti * 70 + tj];
      #pragma unroll
      for (int m = 0; m < COT; m++){
        const bf16* ap = wb + (m * 16 + lm) * 2304 + chunkG * 288 + tap * 32 + lq * 8;
        short8 afr = *(const short8*)ap;
        acc[m] = __builtin_amdgcn_mfma_f32_16x16x32_bf16(afr, bfr, acc[m], 0, 0, 0);
      }
    }
  }
  const int p = y * 64 + px;
  #pragma unroll
  for (int m = 0; m < COT; m++){
    #pragma unroll
    for (int r = 0; r < 4; r++){
      const int co = m * 16 + lq * 4 + r;
      if (co >= co_lim) continue;
      outp[(b * co_lim + co) * 4096 + p] = acc[m][r];
    }
  }
}

__global__ __launch_bounds__(256) void k_coff_m(const void* x, const int* flagp,
    const bf16* woffb, float* offp){
  __shared__ __align__(16) unsigned short xtile[32 * 210];
  float* op = offp + blockIdx.y * 294912;
  const int cc0 = blockIdx.y * 64;
  if (*flagp) conv3_raw<float, 2>((const float*)x, woffb, op, 18, xtile, cc0);
  else        conv3_raw<bf16, 2>((const bf16*)x, woffb, op, 18, xtile, cc0);
}

__global__ __launch_bounds__(256) void k_g1_m(const bf16* xdense,
    const bf16* wg1b, float* abp){
  __shared__ __align__(16) unsigned short xtile[32 * 210];
  float* op = abp + blockIdx.y * 1048576;
  conv3_raw<bf16, 4>(xdense, wg1b, op, 64, xtile, blockIdx.y * 64);
}

// ---------------------------------------------------------------------------
// K1c: merge 4 offset partials + bias -> offc.
// ---------------------------------------------------------------------------
__global__ __launch_bounds__(256) void k_omerge(const float* __restrict__ offp,
    const float* __restrict__ cb, float* __restrict__ offc){
  const int i4 = (blockIdx.x * 256 + threadIdx.x) * 4;
  constexpr int PS = 294912;
  f32x4 a = *(const f32x4*)(offp + i4);
  f32x4 b = *(const f32x4*)(offp + PS + i4);
  f32x4 c = *(const f32x4*)(offp + 2 * PS + i4);
  f32x4 d = *(const f32x4*)(offp + 3 * PS + i4);
  const int co = (i4 >> 12) % 18;
  const float bias = cb[co];
  f32x4 r;
  #pragma unroll
  for (int j = 0; j < 4; j++) r[j] = ((a[j] + b[j]) + c[j]) + d[j] + bias;
  *(f32x4*)(offc + i4) = r;
}

// ---------------------------------------------------------------------------
// K2: deformable conv — tap-major gather (R14, measured 54.5 µs).
// R16: bilinear weights/indices precomputed ONCE per (tap,pos) in LDS
// (phase A); gather threads (8 per pos) read them as broadcast LDS loads
// instead of recomputing 8x (offc loads + floorf + weights). Values and
// FMA expression identical => bit-identical output.
// ---------------------------------------------------------------------------
#define CROWM 600

__global__ __launch_bounds__(256) void k_deform(const bf16* __restrict__ xt,
    const float* __restrict__ offc, const bf16* __restrict__ wdefb,
    bf16* __restrict__ xdir){
  __shared__ __align__(16) float wls[288 * 4];
  __shared__ __align__(16) unsigned short ils[288 * 4];
  __shared__ __align__(16) unsigned short cols[32 * CROWM];
  const int g = blockIdx.y;
  const int q0 = blockIdx.x * 32;
  const int b = q0 >> 12, p0 = q0 & 4095;
  const int t = threadIdx.x;
  // ---- Phase A: 288 (tap,pos) items -> weights + clamped indices in LDS
  for (int item = t; item < 288; item += 256){
    const int tp = item >> 5, ps = item & 31;
    const int p = p0 + ps;
    const int y = p >> 6, xx = p & 63;
    const float dy = offc[(b * 18 + 2 * tp) * 4096 + p];
    const float dx = offc[(b * 18 + 2 * tp + 1) * 4096 + p];
    const float py = (float)(y + tp / 3 - 1) + dy;
    const float px = (float)(xx + tp % 3 - 1) + dx;
    const float y0f = floorf(py), x0f = floorf(px);
    const int y0 = (int)y0f, x0 = (int)x0f;
    const float wy1 = py - y0f, wx1 = px - x0f;
    const float wy0 = 1.f - wy1, wx0 = 1.f - wx1;
    const bool vy0 = (unsigned)y0 < 64u, vy1 = (unsigned)(y0 + 1) < 64u;
    const bool vx0 = (unsigned)x0 < 64u, vx1 = (unsigned)(x0 + 1) < 64u;
    wls[item * 4 + 0] = (vy0 && vx0) ? wy0 * wx0 : 0.f;
    wls[item * 4 + 1] = (vy0 && vx1) ? wy0 * wx1 : 0.f;
    wls[item * 4 + 2] = (vy1 && vx0) ? wy1 * wx0 : 0.f;
    wls[item * 4 + 3] = (vy1 && vx1) ? wy1 * wx1 : 0.f;
    const int yc0 = min(max(y0, 0), 63), yc1 = min(max(y0 + 1, 0), 63);
    const int xc0 = min(max(x0, 0), 63), xc1 = min(max(x0 + 1, 0), 63);
    ils[item * 4 + 0] = (unsigned short)(yc0 * 64 + xc0);
    ils[item * 4 + 1] = (unsigned short)(yc0 * 64 + xc1);
    ils[item * 4 + 2] = (unsigned short)(yc1 * 64 + xc0);
    ils[item * 4 + 3] = (unsigned short)(yc1 * 64 + xc1);
  }
  __syncthreads();
  // ---- Phase B: gather (weights/indices broadcast from LDS)
  {
    const int pos = t & 31, u8 = t >> 5;
    const int c0 = u8 * 8;
    const bf16* xg = xt + (b * 4 + g) * 4096 * 64;
    #pragma unroll
    for (int k = 0; k < 9; k++){
      const int item = k * 32 + pos;
      const f32x4 wv = *(const f32x4*)(wls + item * 4);
      const unsigned short* ip = ils + item * 4;
      short8 s00 = *(const short8*)(xg + (int)ip[0] * 64 + c0);
      short8 s01 = *(const short8*)(xg + (int)ip[1] * 64 + c0);
      short8 s10 = *(const short8*)(xg + (int)ip[2] * 64 + c0);
      short8 s11 = *(const short8*)(xg + (int)ip[3] * 64 + c0);
      u32x4 pkv;
      #pragma unroll
      for (int e = 0; e < 4; e++){
        float v0 = wv[0] * bfe(s00, 2*e)   + wv[1] * bfe(s01, 2*e)
                 + wv[2] * bfe(s10, 2*e)   + wv[3] * bfe(s11, 2*e);
        float v1 = wv[0] * bfe(s00, 2*e+1) + wv[1] * bfe(s01, 2*e+1)
                 + wv[2] * bfe(s10, 2*e+1) + wv[3] * bfe(s11, 2*e+1);
        bf16 h0 = __float2bfloat16(v0), h1 = __float2bfloat16(v1);
        pkv[e] = (unsigned int)*(unsigned short*)&h0
               | ((unsigned int)*(unsigned short*)&h1 << 16);
      }
      *(u32x4*)(cols + pos * CROWM + k * 64 + c0) = pkv;
    }
  }
  __syncthreads();
  // ---- MFMA phase (unchanged)
  {
    const int w = t >> 6;
    const int l = t & 63;
    const int lrow = l & 15;
    const int lhi = l >> 4;
    f32x4 acc0 = {0.f, 0.f, 0.f, 0.f};
    f32x4 acc1 = {0.f, 0.f, 0.f, 0.f};
    const bf16* wr = wdefb + (g * 64 + w * 16 + lrow) * 576;
    const unsigned short* b0p = cols + lrow * CROWM;
    const unsigned short* b1p = cols + (16 + lrow) * CROWM;
    #pragma unroll 2
    for (int kk = 0; kk < 576; kk += 32){
      int ko = kk + lhi * 8;
      short8 a  = *(const short8*)(wr + ko);
      short8 b0 = *(const short8*)(b0p + ko);
      short8 b1 = *(const short8*)(b1p + ko);
      acc0 = __builtin_amdgcn_mfma_f32_16x16x32_bf16(a, b0, acc0, 0, 0, 0);
      acc1 = __builtin_amdgcn_mfma_f32_16x16x32_bf16(a, b1, acc1, 0, 0, 0);
    }
    const int co_base = g * 64 + w * 16 + lhi * 4;
    #pragma unroll
    for (int r = 0; r < 4; r++){
      bf16* xo = xdir + (b * 256 + co_base + r) * 4096 + p0 + lrow;
      xo[0]  = __float2bfloat16(acc0[r]);
      xo[16] = __float2bfloat16(acc1[r]);
    }
  }
}

// ---------------------------------------------------------------------------
// K3: 1x1 conv concat([x_dir, x_prev]) * w_cross — MFMA, grid (256,4),
// async-stage (R12 structure — passing).
// ---------------------------------------------------------------------------
template<typename T>
__device__ __forceinline__ void cross_load(const bf16* __restrict__ xdir,
    const T* __restrict__ xprev, int b, int y, int pos2, int cq, int cc,
    unsigned int* pk){
  #pragma unroll
  for (int c8 = 0; c8 < 8; c8++){
    const int ci = cc + cq * 8 + c8;
    if (ci < 256){
      pk[c8] = *(const unsigned int*)(xdir + (b * 256 + ci) * 4096 + y * 64 + 2 * pos2);
    } else {
      float v0, v1;
      ld2v(xprev + (b * 256 + (ci - 256)) * 4096 + y * 64 + 2 * pos2, v0, v1);
      bf16 h0 = __float2bfloat16(v0), h1 = __float2bfloat16(v1);
      pk[c8] = (unsigned int)*(unsigned short*)&h0
             | ((unsigned int)*(unsigned short*)&h1 << 16);
    }
  }
}

template<typename T>
__device__ __forceinline__ void cross_mfma_body(const bf16* __restrict__ xdir,
    const T* __restrict__ xprev, const bf16* __restrict__ wb,
    bf16* __restrict__ xdense, unsigned short* cols){
  const int bx = blockIdx.x;
  const int b = bx >> 6, y = bx & 63;
  const int co0 = blockIdx.y * 64;
  const int t = threadIdx.x;
  const int l = t & 63, w = t >> 6;
  const int lm = l & 15, lq = l >> 4;
  const int pos2 = t & 31, cq = t >> 5;
  unsigned int* cols32 = (unsigned int*)cols;
  f32x4 acc[4];
  #pragma unroll
  for (int m = 0; m < 4; m++) acc[m] = (f32x4){0.f,0.f,0.f,0.f};
  unsigned int pk[8];
  cross_load(xdir, xprev, b, y, pos2, cq, 0, pk);

  for (int c = 0; c < 8; c++){
    __syncthreads();
    #pragma unroll
    for (int c8 = 0; c8 < 8; c8++)
      cols32[(cq * 8 + c8) * 34 + pos2] = pk[c8];
    __syncthreads();
    if (c < 7) cross_load(xdir, xprev, b, y, pos2, cq, (c + 1) * 64, pk);
    const int cc = c * 64;
    #pragma unroll
    for (int kk = 0; kk < 64; kk += 32){
      short8 bfr;
      #pragma unroll
      for (int j = 0; j < 8; j++)
        bfr[j] = (short)cols[(kk + lq * 8 + j) * 68 + w * 16 + lm];
      #pragma unroll
      for (int m = 0; m < 4; m++){
        const bf16* ap = wb + (co0 + m * 16 + lm) * 512 + cc + kk + lq * 8;
        short8 afr = *(const short8*)ap;
        acc[m] = __builtin_amdgcn_mfma_f32_16x16x32_bf16(afr, bfr, acc[m], 0, 0, 0);
      }
    }
  }
  const int p = y * 64 + w * 16 + lm;
  #pragma unroll
  for (int m = 0; m < 4; m++){
    #pragma unroll
    for (int r = 0; r < 4; r++){
      const int co = co0 + m * 16 + lq * 4 + r;
      xdense[(b * 256 + co) * 4096 + p] = __float2bfloat16(acc[m][r]);
    }
  }
}

__global__ __launch_bounds__(256) void k_cross(const bf16* xdir, const void* xprev,
    const int* flagp, const bf16* wcb, bf16* xdense){
  __shared__ __align__(16) unsigned short cols[64 * 68];
  if (*flagp) cross_mfma_body(xdir, (const float*)xprev, wcb, xdense, cols);
  else        cross_mfma_body(xdir, (const bf16*)xprev, wcb, xdense, cols);
}

// ---------------------------------------------------------------------------
// K5: attn (R8 structure). xdense bf16; xa bf16.
// ---------------------------------------------------------------------------
__global__ __launch_bounds__(256) void k_attn(const float* __restrict__ abp,
    const float* __restrict__ cb1, const float* __restrict__ gam,
    const float* __restrict__ bet, const float* __restrict__ mea,
    const float* __restrict__ var, const float* __restrict__ cwT,
    const float* __restrict__ cb2, const bf16* __restrict__ xdense,
    bf16* __restrict__ xa){
  __shared__ float a_s[64][17];
  const int bx = blockIdx.x;
  const int b = bx >> 8, pc = bx & 255;
  const int p0 = pc * 16;
  const int t = threadIdx.x;
  constexpr int PS = 1048576;
  {
    const int ch = t >> 2;
    const int px0 = (t & 3) * 4;
    const float inv = gam[ch] * rsqrtf(var[ch] + 1e-5f);
    const float sh  = bet[ch] - mea[ch] * inv;
    const float bias = cb1[ch];
    const int ai = (b * 64 + ch) * 4096 + p0 + px0;
    #pragma unroll
    for (int j = 0; j < 4; j++){
      float s = ((abp[ai + j] + abp[PS + ai + j]) + abp[2 * PS + ai + j])
              + abp[3 * PS + ai + j];
      s += bias;
      s = s * inv + sh;
      s = s * sigf(s);
      a_s[ch][px0 + j] = s;
    }
  }
  __syncthreads();
  const int co = t;
  float acc[16];
  #pragma unroll
  for (int i = 0; i < 16; i++) acc[i] = 0.f;
  for (int c = 0; c < 64; c++){
    const float wv = cwT[c * 256 + co];
    #pragma unroll
    for (int i = 0; i < 16; i++) acc[i] += wv * a_s[c][i];
  }
  const float bias2 = cb2[co];
  const int base = (b * 256 + co) * 4096 + p0;
  #pragma unroll
  for (int i = 0; i < 16; i++){
    float attn = sigf(acc[i] + bias2);
    xa[base + i] = __float2bfloat16(b2f(xdense[base + i]) * attn);
  }
}

// ---------------------------------------------------------------------------
// K6: 1x1 conv 256->256 + bias + BN + SiLU + residual — MFMA, grid (256,4),
// async-stage (R12 structure — passing).
// ---------------------------------------------------------------------------
__device__ __forceinline__ void out_load(const bf16* __restrict__ xa,
    int b, int y, int pos2, int cq, int cc, unsigned int* pk){
  #pragma unroll
  for (int c8 = 0; c8 < 8; c8++){
    const int ci = cc + cq * 8 + c8;
    pk[c8] = *(const unsigned int*)(xa + (b * 256 + ci) * 4096 + y * 64 + 2 * pos2);
  }
}

template<typename T>
__device__ __forceinline__ void out_mfma_body(const bf16* __restrict__ xa,
    const bf16* __restrict__ wb, const float* __restrict__ cbv,
    const float* __restrict__ gam, const float* __restrict__ bet,
    const float* __restrict__ mea, const float* __restrict__ var,
    const T* __restrict__ xres, T* __restrict__ outp, unsigned short* cols){
  const int bx = blockIdx.x;
  const int b = bx >> 6, y = bx & 63;
  const int co0 = blockIdx.y * 64;
  const int t = threadIdx.x;
  const int l = t & 63, w = t >> 6;
  const int lm = l & 15, lq = l >> 4;
  const int pos2 = t & 31, cq = t >> 5;
  unsigned int* cols32 = (unsigned int*)cols;
  f32x4 acc[4];
  #pragma unroll
  for (int m = 0; m < 4; m++) acc[m] = (f32x4){0.f,0.f,0.f,0.f};
  unsigned int pk[8];
  out_load(xa, b, y, pos2, cq, 0, pk);

  for (int c = 0; c < 4; c++){
    __syncthreads();
    #pragma unroll
    for (int c8 = 0; c8 < 8; c8++)
      cols32[(cq * 8 + c8) * 34 + pos2] = pk[c8];
    __syncthreads();
    if (c < 3) out_load(xa, b, y, pos2, cq, (c + 1) * 64, pk);
    const int cc = c * 64;
    #pragma unroll
    for (int kk = 0; kk < 64; kk += 32){
      short8 bfr;
      #pragma unroll
      for (int j = 0; j < 8; j++)
        bfr[j] = (short)cols[(kk + lq * 8 + j) * 68 + w * 16 + lm];
      #pragma unroll
      for (int m = 0; m < 4; m++){
        const bf16* ap = wb + (co0 + m * 16 + lm) * 256 + cc + kk + lq * 8;
        short8 afr = *(const short8*)ap;
        acc[m] = __builtin_amdgcn_mfma_f32_16x16x32_bf16(afr, bfr, acc[m], 0, 0, 0);
      }
    }
  }
  const int p = y * 64 + w * 16 + lm;
  #pragma unroll
  for (int m = 0; m < 4; m++){
    #pragma unroll
    for (int r = 0; r < 4; r++){
      const int co = co0 + m * 16 + lq * 4 + r;
      float inv = gam[co] * rsqrtf(var[co] + 1e-5f);
      float v = acc[m][r] + cbv[co];
      v = v * inv + (bet[co] - mea[co] * inv);
      v = v * sigf(v);
      const int idx = (b * 256 + co) * 4096 + p;
      stv(outp, idx, v + ldv(xres, idx));
    }
  }
}

__global__ __launch_bounds__(256) void k_out(const bf16* xa, const bf16* wob,
    const float* cb, const float* gam, const float* bet, const float* mea,
    const float* var, const void* xres, void* out, const int* flagp){
  __shared__ __align__(16) unsigned short cols[64 * 68];
  if (*flagp) out_mfma_body(xa, wob, cb, gam, bet, mea, var,
                            (const float*)xres, (float*)out, cols);
  else        out_mfma_body(xa, wob, cb, gam, bet, mea, var,
                            (const bf16*)xres, (bf16*)out, cols);
}

// ---------------------------------------------------------------------------
extern "C" void kernel_launch(void* const* d_in, const int* in_sizes, int n_in,
                              void* d_out, int out_size, void* d_ws, size_t ws_size,
                              hipStream_t stream) {
  const void* x      = d_in[0];
  const void* x_prev = d_in[1];

  float* ws   = (float*)d_ws;
  int*   flag = (int*)ws;                 // ws[0..15] reserved
  float* cpar = ws + 16;                  // canonical fp32 params (551264 f)
  float* cb_off   = cpar + 41472;
  float* cb_g1    = cpar + 467488;
  float* cg1_gam  = cpar + 467552;
  float* cg1_bet  = cpar + 467616;
  float* cg1_mea  = cpar + 467680;
  float* cg1_var  = cpar + 467744;
  float* cb_g2    = cpar + 484192;
  float* cb_out   = cpar + 549984;
  float* co_gam   = cpar + 550240;
  float* co_bet   = cpar + 550496;
  float* co_mea   = cpar + 550752;
  float* co_var   = cpar + 551008;

  float* cwT     = ws + 16 + 551264;                // 16384 f (w_g2 transposed)
  bf16*  wdefb   = (bf16*)(ws + 567664);            // 73728 f
  bf16*  woffb   = (bf16*)(ws + 641392);            // 36864 f
  bf16*  wg1b    = (bf16*)(ws + 678256);            // 73728 f
  bf16*  wcrossb = (bf16*)(ws + 751984);            // 65536 f
  bf16*  woutb   = (bf16*)(ws + 817520);            // 32768 f
  float* base    = ws + 850288;
  float* offp    = base;                    // 4 x 294912  = 1179648 f
  float* offc    = offp + 1179648;          // 294912 f
  float* abp     = offc + 294912;           // 4 x 1048576 = 4194304 f
  bf16*  xdirb   = (bf16*)(abp + 4194304);  // 4194304 hw = 2097152 f
  bf16*  xdenseb = (bf16*)(abp + 6291456);  // 4194304 hw = 2097152 f
  bf16*  xtb     = (bf16*)(abp + 8388608);  // 4194304 hw = 2097152 f
  bf16*  xab     = xdirb;                   // reuse (xdir dead after K3)

  ParamSrc ps;
  for (int i = 0; i < 18; i++) ps.p[i] = d_in[2 + i];

  k_detect<<<dim3(1), 256, 0, stream>>>((const unsigned short*)x, flag);
  k_convert<<<dim3(96, 24), 256, 0, stream>>>(ps, flag, cpar, wdefb, woffb,
                                              wg1b, wcrossb, woutb, cwT);
  k_xt<<<dim3(1024), 256, 0, stream>>>(x, flag, xtb);
  k_coff_m<<<dim3(256, 4), 256, 0, stream>>>(x, flag, woffb, offp);
  k_omerge<<<dim3(288), 256, 0, stream>>>(offp, cb_off, offc);
  k_deform<<<dim3(512, 4), 256, 0, stream>>>(xtb, offc, wdefb, xdirb);
  k_cross<<<dim3(256, 4), 256, 0, stream>>>(xdirb, x_prev, flag, wcrossb, xdenseb);
  k_g1_m<<<dim3(256, 4), 256, 0, stream>>>(xdenseb, wg1b, abp);
  k_attn<<<dim3(1024), 256, 0, stream>>>(abp, cb_g1, cg1_gam, cg1_bet, cg1_mea,
                                         cg1_var, cwT, cb_g2, xdenseb, xab);
  k_out<<<dim3(256, 4), 256, 0, stream>>>(xab, woutb, cb_out, co_gam, co_bet,
                                          co_mea, co_var, x, d_out, flag);
}

// Round 17
// 323.657 us; speedup vs baseline: 1.0183x; 1.0183x over previous
//
#include <hip/hip_runtime.h>
#include <hip/hip_bf16.h>

using bf16 = __hip_bfloat16;
typedef __attribute__((ext_vector_type(8))) short short8;
typedef __attribute__((ext_vector_type(4))) float f32x4;
typedef __attribute__((ext_vector_type(4))) unsigned int u32x4;

__device__ __forceinline__ float b2f(bf16 v){ return __bfloat162float(v); }
__device__ __forceinline__ float sigf(float v){ return 1.f/(1.f + __expf(-v)); }
__device__ __forceinline__ float ldv(const float* p, int i){ return p[i]; }
__device__ __forceinline__ float ldv(const bf16* p, int i){ return b2f(p[i]); }
__device__ __forceinline__ void stv(float* p, int i, float v){ p[i] = v; }
__device__ __forceinline__ void stv(bf16* p, int i, float v){ p[i] = __float2bfloat16(v); }
__device__ __forceinline__ float bfe(short8 v, int j){
  unsigned short s = (unsigned short)v[j];
  return b2f(*(bf16*)&s);
}

__device__ __forceinline__ void ld2v(const float* p, float& a, float& b){
  float2 v = *(const float2*)p; a = v.x; b = v.y;
}
__device__ __forceinline__ void ld2v(const bf16* p, float& a, float& b){
  unsigned int u = *(const unsigned int*)p;
  unsigned short s0 = (unsigned short)(u & 0xFFFF), s1 = (unsigned short)(u >> 16);
  a = b2f(*(bf16*)&s0); b = b2f(*(bf16*)&s1);
}
__device__ __forceinline__ void ld8(const bf16* s, unsigned int* pk){
  short8 v = *(const short8*)s;
  #pragma unroll
  for (int e = 0; e < 4; e++)
    pk[e] = (unsigned int)(unsigned short)v[2*e]
          | ((unsigned int)(unsigned short)v[2*e+1] << 16);
}
__device__ __forceinline__ void ld8(const float* s, unsigned int* pk){
  f32x4 a = *(const f32x4*)s, c = *(const f32x4*)(s + 4);
  float vals[8] = {a[0],a[1],a[2],a[3],c[0],c[1],c[2],c[3]};
  #pragma unroll
  for (int e = 0; e < 4; e++){
    bf16 h0 = __float2bfloat16(vals[2*e]), h1 = __float2bfloat16(vals[2*e+1]);
    pk[e] = (unsigned int)*(unsigned short*)&h0
          | ((unsigned int)*(unsigned short*)&h1 << 16);
  }
}

// ---------------------------------------------------------------------------
// K0: dtype detect. flag=1 => inputs are f32.
// ---------------------------------------------------------------------------
__global__ __launch_bounds__(256) void k_detect(const unsigned short* xs, int* flag){
  __shared__ int cnt;
  if (threadIdx.x == 0) cnt = 0;
  __syncthreads();
  int local = 0;
  for (int i = threadIdx.x; i < 16384; i += 256){
    if (((xs[i] >> 7) & 0xFF) == 0xFF) local++;
  }
  if (local) atomicAdd(&cnt, local);
  __syncthreads();
  if (threadIdx.x == 0) *flag = (cnt > 0) ? 1 : 0;
}

// ---------------------------------------------------------------------------
// K0b: canonicalize params. 18 = w_def REMAPPED tap-major [co][tap*64+c];
// 19/20 = w_off/w_g1 remapped [co][chunk][tap][c32]; 23 = w_g2 transposed.
// ---------------------------------------------------------------------------
struct ParamSrc { const void* p[18]; };

__global__ __launch_bounds__(256) void k_convert(ParamSrc ps, const int* flagp,
    float* cpar, bf16* wdefb, bf16* woffb, bf16* wg1b, bf16* wcrossb, bf16* woutb,
    float* cwT){
  static constexpr int n[24]   = {41472,18,147456,131072,147456,64,64,64,64,64,
                                  16384,256,65536,256,256,256,256,256,
                                  147456,73728,147456,131072,65536,16384};
  static constexpr int off[18] = {0,41472,41504,188960,320032,467488,467552,467616,
                                  467680,467744,467808,484192,484448,549984,550240,
                                  550496,550752,551008};
  const int s = blockIdx.y;
  const bool f32 = (*flagp != 0);
  if (s == 23){
    for (int i = blockIdx.x * 256 + threadIdx.x; i < 16384; i += gridDim.x * 256){
      const int c = i >> 8, co = i & 255;
      if (f32) cwT[i] = ((const float*)ps.p[10])[co * 64 + c];
      else     cwT[i] = b2f(((const bf16*)ps.p[10])[co * 64 + c]);
    }
    return;
  }
  if (s >= 18){
    static constexpr int srcs[5] = {2, 0, 4, 3, 12};
    const int src_slot = srcs[s - 18];
    bf16* dst = (s == 18) ? wdefb : (s == 19) ? woffb : (s == 20) ? wg1b
              : (s == 21) ? wcrossb : woutb;
    const int nsrc = (s == 19) ? 41472 : n[s];
    for (int i = blockIdx.x * 256 + threadIdx.x; i < n[s]; i += gridDim.x * 256){
      int srcIdx = i;
      if (s == 19 || s == 20){
        const int co = i / 2304, rem = i % 2304;
        const int chunk = rem / 288, r2 = rem % 288;
        const int tap = r2 >> 5, cl = r2 & 31;
        srcIdx = co * 2304 + (chunk * 32 + cl) * 9 + tap;
      } else if (s == 18){
        const int co = i / 576, rem = i % 576;
        const int tap = rem >> 6, c = rem & 63;
        srcIdx = co * 576 + c * 9 + tap;
      }
      if (f32){
        const float* src = (const float*)ps.p[src_slot];
        dst[i] = (srcIdx < nsrc) ? __float2bfloat16(src[srcIdx]) : __float2bfloat16(0.f);
      } else {
        const bf16* src = (const bf16*)ps.p[src_slot];
        dst[i] = (srcIdx < nsrc) ? src[srcIdx] : __float2bfloat16(0.f);
      }
    }
    return;
  }
  float* dst = cpar + off[s];
  if (f32){
    const float* src = (const float*)ps.p[s];
    for (int i = blockIdx.x * 256 + threadIdx.x; i < n[s]; i += gridDim.x * 256)
      dst[i] = src[i];
  } else {
    const bf16* src = (const bf16*)ps.p[s];
    for (int i = blockIdx.x * 256 + threadIdx.x; i < n[s]; i += gridDim.x * 256)
      dst[i] = b2f(src[i]);
  }
}

// ---------------------------------------------------------------------------
// K1b: NHWC bf16 staging for deform gather: x_t[b][g][p=4096][cg=64].
// ---------------------------------------------------------------------------
template<typename T>
__device__ __forceinline__ void xt_body(const T* __restrict__ x, bf16* __restrict__ xt){
  __shared__ float lds[64][65];
  const int bx = blockIdx.x;
  const int b = bx >> 8, y = (bx >> 2) & 63, g = bx & 3;
  const int t = threadIdx.x;
  const int px = t & 63, cq = t >> 6;
  #pragma unroll
  for (int it = 0; it < 16; it++){
    const int ch = cq * 16 + it;
    lds[ch][px] = ldv(x, ((b * 256 + g * 64 + ch) * 64 + y) * 64 + px);
  }
  __syncthreads();
  const int ch = t & 63, pb = t >> 6;
  bf16* ob = xt + ((b * 4 + g) * 4096 + y * 64) * 64 + ch;
  #pragma unroll
  for (int i = 0; i < 16; i++){
    const int p = pb * 16 + i;
    ob[p * 64] = __float2bfloat16(lds[ch][p]);
  }
}

__global__ __launch_bounds__(256) void k_xt(const void* x, const int* flagp, bf16* xt){
  if (*flagp) xt_body((const float*)x, xt);
  else        xt_body((const bf16*)x, xt);
}

// ---------------------------------------------------------------------------
// conv3 RAW split-K, TILE-STAGED (R12/R15 structure — measured good).
// ---------------------------------------------------------------------------
template<typename T, int COT>
__device__ __forceinline__ void conv3_raw(const T* __restrict__ xin,
    const bf16* __restrict__ wb, float* __restrict__ outp, int co_lim,
    unsigned short* xt16, int cc_begin){
  const int bx = blockIdx.x;
  const int b = bx >> 6, y = bx & 63;
  const int t = threadIdx.x;
  const int l = t & 63, w = t >> 6;
  const int lm = l & 15, lq = l >> 4;
  const int px = w * 16 + lm;
  f32x4 acc[COT];
  #pragma unroll
  for (int m = 0; m < COT; m++) acc[m] = (f32x4){0.f,0.f,0.f,0.f};

  #pragma unroll
  for (int ch_i = 0; ch_i < 2; ch_i++){
    const int cc = cc_begin + ch_i * 32;
    __syncthreads();
    if (t < 96){
      const int c = t / 3, r = t - c * 3;
      xt16[c * 210 + r * 70 + 3]  = 0;
      xt16[c * 210 + r * 70 + 68] = 0;
    }
    #pragma unroll
    for (int it = 0; it < 3; it++){
      const int u = t + it * 256;
      const int pb = u & 7;
      const int cr = u >> 3;
      const int c = cr / 3, r = cr - c * 3;
      const int yy = y + r - 1;
      const int px0 = pb * 8;
      unsigned int pk[4];
      if ((unsigned)yy < 64u){
        ld8(xin + (b * 256 + cc + c) * 4096 + yy * 64 + px0, pk);
      } else {
        pk[0] = pk[1] = pk[2] = pk[3] = 0;
      }
      unsigned int* dp = (unsigned int*)(xt16 + c * 210 + r * 70 + 4 + px0);
      dp[0] = pk[0]; dp[1] = pk[1]; dp[2] = pk[2]; dp[3] = pk[3];
    }
    __syncthreads();
    const int chunkG = cc >> 5;
    const unsigned short* bt = xt16 + 3 + px;
    #pragma unroll
    for (int tap = 0; tap < 9; tap++){
      const int ti = tap / 3, tj = tap - ti * 3;
      short8 bfr;
      #pragma unroll
      for (int j = 0; j < 8; j++)
        bfr[j] = (short)bt[(lq * 8 + j) * 210 + ti * 70 + tj];
      #pragma unroll
      for (int m = 0; m < COT; m++){
        const bf16* ap = wb + (m * 16 + lm) * 2304 + chunkG * 288 + tap * 32 + lq * 8;
        short8 afr = *(const short8*)ap;
        acc[m] = __builtin_amdgcn_mfma_f32_16x16x32_bf16(afr, bfr, acc[m], 0, 0, 0);
      }
    }
  }
  const int p = y * 64 + px;
  #pragma unroll
  for (int m = 0; m < COT; m++){
    #pragma unroll
    for (int r = 0; r < 4; r++){
      const int co = m * 16 + lq * 4 + r;
      if (co >= co_lim) continue;
      outp[(b * co_lim + co) * 4096 + p] = acc[m][r];
    }
  }
}

__global__ __launch_bounds__(256) void k_coff_m(const void* x, const int* flagp,
    const bf16* woffb, float* offp){
  __shared__ __align__(16) unsigned short xtile[32 * 210];
  float* op = offp + blockIdx.y * 294912;
  const int cc0 = blockIdx.y * 64;
  if (*flagp) conv3_raw<float, 2>((const float*)x, woffb, op, 18, xtile, cc0);
  else        conv3_raw<bf16, 2>((const bf16*)x, woffb, op, 18, xtile, cc0);
}

__global__ __launch_bounds__(256) void k_g1_m(const bf16* xdense,
    const bf16* wg1b, float* abp){
  __shared__ __align__(16) unsigned short xtile[32 * 210];
  float* op = abp + blockIdx.y * 1048576;
  conv3_raw<bf16, 4>(xdense, wg1b, op, 64, xtile, blockIdx.y * 64);
}

// ---------------------------------------------------------------------------
// K1c: merge 4 offset partials + bias -> offc.
// ---------------------------------------------------------------------------
__global__ __launch_bounds__(256) void k_omerge(const float* __restrict__ offp,
    const float* __restrict__ cb, float* __restrict__ offc){
  const int i4 = (blockIdx.x * 256 + threadIdx.x) * 4;
  constexpr int PS = 294912;
  f32x4 a = *(const f32x4*)(offp + i4);
  f32x4 b = *(const f32x4*)(offp + PS + i4);
  f32x4 c = *(const f32x4*)(offp + 2 * PS + i4);
  f32x4 d = *(const f32x4*)(offp + 3 * PS + i4);
  const int co = (i4 >> 12) % 18;
  const float bias = cb[co];
  f32x4 r;
  #pragma unroll
  for (int j = 0; j < 4; j++) r[j] = ((a[j] + b[j]) + c[j]) + d[j] + bias;
  *(f32x4*)(offc + i4) = r;
}

// ---------------------------------------------------------------------------
// K2: deformable conv — merged bf16 NHWC gather, TAP-MAJOR K-layout
// (R15 structure — measured best: 54.4 µs, occupancy 37%).
// ---------------------------------------------------------------------------
#define CROWM 600

__global__ __launch_bounds__(256) void k_deform(const bf16* __restrict__ xt,
    const float* __restrict__ offc, const bf16* __restrict__ wdefb,
    bf16* __restrict__ xdir){
  __shared__ __align__(16) unsigned short cols[32 * CROWM];
  const int g = blockIdx.y;
  const int q0 = blockIdx.x * 32;
  const int b = q0 >> 12, p0 = q0 & 4095;
  const int t = threadIdx.x;
  {
    const int pos = t & 31, u8 = t >> 5;
    const int c0 = u8 * 8;
    const int p = p0 + pos;
    const int y = p >> 6, xx = p & 63;
    const float* ob = offc + b * 18 * 4096 + p;
    const bf16* xg = xt + (b * 4 + g) * 4096 * 64;
    #pragma unroll
    for (int k = 0; k < 9; k++){
      float dy = ob[(2 * k) * 4096];
      float dx = ob[(2 * k + 1) * 4096];
      float py = (float)(y + k / 3 - 1) + dy;
      float px = (float)(xx + k % 3 - 1) + dx;
      float y0f = floorf(py), x0f = floorf(px);
      int y0 = (int)y0f, x0 = (int)x0f;
      float wy1 = py - y0f, wx1 = px - x0f;
      float wy0 = 1.f - wy1, wx0 = 1.f - wx1;
      bool vy0 = (unsigned)y0 < 64u, vy1 = (unsigned)(y0 + 1) < 64u;
      bool vx0 = (unsigned)x0 < 64u, vx1 = (unsigned)(x0 + 1) < 64u;
      float w00 = (vy0 && vx0) ? wy0 * wx0 : 0.f;
      float w01 = (vy0 && vx1) ? wy0 * wx1 : 0.f;
      float w10 = (vy1 && vx0) ? wy1 * wx0 : 0.f;
      float w11 = (vy1 && vx1) ? wy1 * wx1 : 0.f;
      int yc0 = min(max(y0, 0), 63), yc1 = min(max(y0 + 1, 0), 63);
      int xc0 = min(max(x0, 0), 63), xc1 = min(max(x0 + 1, 0), 63);
      int i00 = yc0 * 64 + xc0, i01 = yc0 * 64 + xc1;
      int i10 = yc1 * 64 + xc0, i11 = yc1 * 64 + xc1;
      short8 s00 = *(const short8*)(xg + i00 * 64 + c0);
      short8 s01 = *(const short8*)(xg + i01 * 64 + c0);
      short8 s10 = *(const short8*)(xg + i10 * 64 + c0);
      short8 s11 = *(const short8*)(xg + i11 * 64 + c0);
      u32x4 pkv;
      #pragma unroll
      for (int e = 0; e < 4; e++){
        float v0 = w00 * bfe(s00, 2*e)   + w01 * bfe(s01, 2*e)
                 + w10 * bfe(s10, 2*e)   + w11 * bfe(s11, 2*e);
        float v1 = w00 * bfe(s00, 2*e+1) + w01 * bfe(s01, 2*e+1)
                 + w10 * bfe(s10, 2*e+1) + w11 * bfe(s11, 2*e+1);
        bf16 h0 = __float2bfloat16(v0), h1 = __float2bfloat16(v1);
        pkv[e] = (unsigned int)*(unsigned short*)&h0
               | ((unsigned int)*(unsigned short*)&h1 << 16);
      }
      *(u32x4*)(cols + pos * CROWM + k * 64 + c0) = pkv;
    }
  }
  __syncthreads();
  {
    const int w = t >> 6;
    const int l = t & 63;
    const int lrow = l & 15;
    const int lhi = l >> 4;
    f32x4 acc0 = {0.f, 0.f, 0.f, 0.f};
    f32x4 acc1 = {0.f, 0.f, 0.f, 0.f};
    const bf16* wr = wdefb + (g * 64 + w * 16 + lrow) * 576;
    const unsigned short* b0p = cols + lrow * CROWM;
    const unsigned short* b1p = cols + (16 + lrow) * CROWM;
    #pragma unroll 2
    for (int kk = 0; kk < 576; kk += 32){
      int ko = kk + lhi * 8;
      short8 a  = *(const short8*)(wr + ko);
      short8 b0 = *(const short8*)(b0p + ko);
      short8 b1 = *(const short8*)(b1p + ko);
      acc0 = __builtin_amdgcn_mfma_f32_16x16x32_bf16(a, b0, acc0, 0, 0, 0);
      acc1 = __builtin_amdgcn_mfma_f32_16x16x32_bf16(a, b1, acc1, 0, 0, 0);
    }
    const int co_base = g * 64 + w * 16 + lhi * 4;
    #pragma unroll
    for (int r = 0; r < 4; r++){
      bf16* xo = xdir + (b * 256 + co_base + r) * 4096 + p0 + lrow;
      xo[0]  = __float2bfloat16(acc0[r]);
      xo[16] = __float2bfloat16(acc1[r]);
    }
  }
}

// ---------------------------------------------------------------------------
// K3: 1x1 conv concat([x_dir, x_prev]) * w_cross — MFMA, grid (256,4),
// async-stage (R12 structure — passing).
// ---------------------------------------------------------------------------
template<typename T>
__device__ __forceinline__ void cross_load(const bf16* __restrict__ xdir,
    const T* __restrict__ xprev, int b, int y, int pos2, int cq, int cc,
    unsigned int* pk){
  #pragma unroll
  for (int c8 = 0; c8 < 8; c8++){
    const int ci = cc + cq * 8 + c8;
    if (ci < 256){
      pk[c8] = *(const unsigned int*)(xdir + (b * 256 + ci) * 4096 + y * 64 + 2 * pos2);
    } else {
      float v0, v1;
      ld2v(xprev + (b * 256 + (ci - 256)) * 4096 + y * 64 + 2 * pos2, v0, v1);
      bf16 h0 = __float2bfloat16(v0), h1 = __float2bfloat16(v1);
      pk[c8] = (unsigned int)*(unsigned short*)&h0
             | ((unsigned int)*(unsigned short*)&h1 << 16);
    }
  }
}

template<typename T>
__device__ __forceinline__ void cross_mfma_body(const bf16* __restrict__ xdir,
    const T* __restrict__ xprev, const bf16* __restrict__ wb,
    bf16* __restrict__ xdense, unsigned short* cols){
  const int bx = blockIdx.x;
  const int b = bx >> 6, y = bx & 63;
  const int co0 = blockIdx.y * 64;
  const int t = threadIdx.x;
  const int l = t & 63, w = t >> 6;
  const int lm = l & 15, lq = l >> 4;
  const int pos2 = t & 31, cq = t >> 5;
  unsigned int* cols32 = (unsigned int*)cols;
  f32x4 acc[4];
  #pragma unroll
  for (int m = 0; m < 4; m++) acc[m] = (f32x4){0.f,0.f,0.f,0.f};
  unsigned int pk[8];
  cross_load(xdir, xprev, b, y, pos2, cq, 0, pk);

  for (int c = 0; c < 8; c++){
    __syncthreads();
    #pragma unroll
    for (int c8 = 0; c8 < 8; c8++)
      cols32[(cq * 8 + c8) * 34 + pos2] = pk[c8];
    __syncthreads();
    if (c < 7) cross_load(xdir, xprev, b, y, pos2, cq, (c + 1) * 64, pk);
    const int cc = c * 64;
    #pragma unroll
    for (int kk = 0; kk < 64; kk += 32){
      short8 bfr;
      #pragma unroll
      for (int j = 0; j < 8; j++)
        bfr[j] = (short)cols[(kk + lq * 8 + j) * 68 + w * 16 + lm];
      #pragma unroll
      for (int m = 0; m < 4; m++){
        const bf16* ap = wb + (co0 + m * 16 + lm) * 512 + cc + kk + lq * 8;
        short8 afr = *(const short8*)ap;
        acc[m] = __builtin_amdgcn_mfma_f32_16x16x32_bf16(afr, bfr, acc[m], 0, 0, 0);
      }
    }
  }
  const int p = y * 64 + w * 16 + lm;
  #pragma unroll
  for (int m = 0; m < 4; m++){
    #pragma unroll
    for (int r = 0; r < 4; r++){
      const int co = co0 + m * 16 + lq * 4 + r;
      xdense[(b * 256 + co) * 4096 + p] = __float2bfloat16(acc[m][r]);
    }
  }
}

__global__ __launch_bounds__(256) void k_cross(const bf16* xdir, const void* xprev,
    const int* flagp, const bf16* wcb, bf16* xdense){
  __shared__ __align__(16) unsigned short cols[64 * 68];
  if (*flagp) cross_mfma_body(xdir, (const float*)xprev, wcb, xdense, cols);
  else        cross_mfma_body(xdir, (const bf16*)xprev, wcb, xdense, cols);
}

// ---------------------------------------------------------------------------
// K5: attn (R8 structure). xdense bf16; xa bf16.
// ---------------------------------------------------------------------------
__global__ __launch_bounds__(256) void k_attn(const float* __restrict__ abp,
    const float* __restrict__ cb1, const float* __restrict__ gam,
    const float* __restrict__ bet, const float* __restrict__ mea,
    const float* __restrict__ var, const float* __restrict__ cwT,
    const float* __restrict__ cb2, const bf16* __restrict__ xdense,
    bf16* __restrict__ xa){
  __shared__ float a_s[64][17];
  const int bx = blockIdx.x;
  const int b = bx >> 8, pc = bx & 255;
  const int p0 = pc * 16;
  const int t = threadIdx.x;
  constexpr int PS = 1048576;
  {
    const int ch = t >> 2;
    const int px0 = (t & 3) * 4;
    const float inv = gam[ch] * rsqrtf(var[ch] + 1e-5f);
    const float sh  = bet[ch] - mea[ch] * inv;
    const float bias = cb1[ch];
    const int ai = (b * 64 + ch) * 4096 + p0 + px0;
    #pragma unroll
    for (int j = 0; j < 4; j++){
      float s = ((abp[ai + j] + abp[PS + ai + j]) + abp[2 * PS + ai + j])
              + abp[3 * PS + ai + j];
      s += bias;
      s = s * inv + sh;
      s = s * sigf(s);
      a_s[ch][px0 + j] = s;
    }
  }
  __syncthreads();
  const int co = t;
  float acc[16];
  #pragma unroll
  for (int i = 0; i < 16; i++) acc[i] = 0.f;
  for (int c = 0; c < 64; c++){
    const float wv = cwT[c * 256 + co];
    #pragma unroll
    for (int i = 0; i < 16; i++) acc[i] += wv * a_s[c][i];
  }
  const float bias2 = cb2[co];
  const int base = (b * 256 + co) * 4096 + p0;
  #pragma unroll
  for (int i = 0; i < 16; i++){
    float attn = sigf(acc[i] + bias2);
    xa[base + i] = __float2bfloat16(b2f(xdense[base + i]) * attn);
  }
}

// ---------------------------------------------------------------------------
// K6: 1x1 conv 256->256 + bias + BN + SiLU + residual — MFMA, grid (256,4),
// async-stage (R12 structure — passing).
// ---------------------------------------------------------------------------
__device__ __forceinline__ void out_load(const bf16* __restrict__ xa,
    int b, int y, int pos2, int cq, int cc, unsigned int* pk){
  #pragma unroll
  for (int c8 = 0; c8 < 8; c8++){
    const int ci = cc + cq * 8 + c8;
    pk[c8] = *(const unsigned int*)(xa + (b * 256 + ci) * 4096 + y * 64 + 2 * pos2);
  }
}

template<typename T>
__device__ __forceinline__ void out_mfma_body(const bf16* __restrict__ xa,
    const bf16* __restrict__ wb, const float* __restrict__ cbv,
    const float* __restrict__ gam, const float* __restrict__ bet,
    const float* __restrict__ mea, const float* __restrict__ var,
    const T* __restrict__ xres, T* __restrict__ outp, unsigned short* cols){
  const int bx = blockIdx.x;
  const int b = bx >> 6, y = bx & 63;
  const int co0 = blockIdx.y * 64;
  const int t = threadIdx.x;
  const int l = t & 63, w = t >> 6;
  const int lm = l & 15, lq = l >> 4;
  const int pos2 = t & 31, cq = t >> 5;
  unsigned int* cols32 = (unsigned int*)cols;
  f32x4 acc[4];
  #pragma unroll
  for (int m = 0; m < 4; m++) acc[m] = (f32x4){0.f,0.f,0.f,0.f};
  unsigned int pk[8];
  out_load(xa, b, y, pos2, cq, 0, pk);

  for (int c = 0; c < 4; c++){
    __syncthreads();
    #pragma unroll
    for (int c8 = 0; c8 < 8; c8++)
      cols32[(cq * 8 + c8) * 34 + pos2] = pk[c8];
    __syncthreads();
    if (c < 3) out_load(xa, b, y, pos2, cq, (c + 1) * 64, pk);
    const int cc = c * 64;
    #pragma unroll
    for (int kk = 0; kk < 64; kk += 32){
      short8 bfr;
      #pragma unroll
      for (int j = 0; j < 8; j++)
        bfr[j] = (short)cols[(kk + lq * 8 + j) * 68 + w * 16 + lm];
      #pragma unroll
      for (int m = 0; m < 4; m++){
        const bf16* ap = wb + (co0 + m * 16 + lm) * 256 + cc + kk + lq * 8;
        short8 afr = *(const short8*)ap;
        acc[m] = __builtin_amdgcn_mfma_f32_16x16x32_bf16(afr, bfr, acc[m], 0, 0, 0);
      }
    }
  }
  const int p = y * 64 + w * 16 + lm;
  #pragma unroll
  for (int m = 0; m < 4; m++){
    #pragma unroll
    for (int r = 0; r < 4; r++){
      const int co = co0 + m * 16 + lq * 4 + r;
      float inv = gam[co] * rsqrtf(var[co] + 1e-5f);
      float v = acc[m][r] + cbv[co];
      v = v * inv + (bet[co] - mea[co] * inv);
      v = v * sigf(v);
      const int idx = (b * 256 + co) * 4096 + p;
      stv(outp, idx, v + ldv(xres, idx));
    }
  }
}

__global__ __launch_bounds__(256) void k_out(const bf16* xa, const bf16* wob,
    const float* cb, const float* gam, const float* bet, const float* mea,
    const float* var, const void* xres, void* out, const int* flagp){
  __shared__ __align__(16) unsigned short cols[64 * 68];
  if (*flagp) out_mfma_body(xa, wob, cb, gam, bet, mea, var,
                            (const float*)xres, (float*)out, cols);
  else        out_mfma_body(xa, wob, cb, gam, bet, mea, var,
                            (const bf16*)xres, (bf16*)out, cols);
}

// ---------------------------------------------------------------------------
extern "C" void kernel_launch(void* const* d_in, const int* in_sizes, int n_in,
                              void* d_out, int out_size, void* d_ws, size_t ws_size,
                              hipStream_t stream) {
  const void* x      = d_in[0];
  const void* x_prev = d_in[1];

  float* ws   = (float*)d_ws;
  int*   flag = (int*)ws;                 // ws[0..15] reserved
  float* cpar = ws + 16;                  // canonical fp32 params (551264 f)
  float* cb_off   = cpar + 41472;
  float* cb_g1    = cpar + 467488;
  float* cg1_gam  = cpar + 467552;
  float* cg1_bet  = cpar + 467616;
  float* cg1_mea  = cpar + 467680;
  float* cg1_var  = cpar + 467744;
  float* cb_g2    = cpar + 484192;
  float* cb_out   = cpar + 549984;
  float* co_gam   = cpar + 550240;
  float* co_bet   = cpar + 550496;
  float* co_mea   = cpar + 550752;
  float* co_var   = cpar + 551008;

  float* cwT     = ws + 16 + 551264;                // 16384 f (w_g2 transposed)
  bf16*  wdefb   = (bf16*)(ws + 567664);            // 73728 f
  bf16*  woffb   = (bf16*)(ws + 641392);            // 36864 f
  bf16*  wg1b    = (bf16*)(ws + 678256);            // 73728 f
  bf16*  wcrossb = (bf16*)(ws + 751984);            // 65536 f
  bf16*  woutb   = (bf16*)(ws + 817520);            // 32768 f
  float* base    = ws + 850288;
  float* offp    = base;                    // 4 x 294912  = 1179648 f
  float* offc    = offp + 1179648;          // 294912 f
  float* abp     = offc + 294912;           // 4 x 1048576 = 4194304 f
  bf16*  xdirb   = (bf16*)(abp + 4194304);  // 4194304 hw = 2097152 f
  bf16*  xdenseb = (bf16*)(abp + 6291456);  // 4194304 hw = 2097152 f
  bf16*  xtb     = (bf16*)(abp + 8388608);  // 4194304 hw = 2097152 f
  bf16*  xab     = xdirb;                   // reuse (xdir dead after K3)

  ParamSrc ps;
  for (int i = 0; i < 18; i++) ps.p[i] = d_in[2 + i];

  k_detect<<<dim3(1), 256, 0, stream>>>((const unsigned short*)x, flag);
  k_convert<<<dim3(96, 24), 256, 0, stream>>>(ps, flag, cpar, wdefb, woffb,
                                              wg1b, wcrossb, woutb, cwT);
  k_xt<<<dim3(1024), 256, 0, stream>>>(x, flag, xtb);
  k_coff_m<<<dim3(256, 4), 256, 0, stream>>>(x, flag, woffb, offp);
  k_omerge<<<dim3(288), 256, 0, stream>>>(offp, cb_off, offc);
  k_deform<<<dim3(512, 4), 256, 0, stream>>>(xtb, offc, wdefb, xdirb);
  k_cross<<<dim3(256, 4), 256, 0, stream>>>(xdirb, x_prev, flag, wcrossb, xdenseb);
  k_g1_m<<<dim3(256, 4), 256, 0, stream>>>(xdenseb, wg1b, abp);
  k_attn<<<dim3(1024), 256, 0, stream>>>(abp, cb_g1, cg1_gam, cg1_bet, cg1_mea,
                                         cg1_var, cwT, cb_g2, xdenseb, xab);
  k_out<<<dim3(256, 4), 256, 0, stream>>>(xab, woutb, cb_out, co_gam, co_bet,
                                          co_mea, co_var, x, d_out, flag);
}